// Round 11
// baseline (99.994 us; speedup 1.0000x reference)
//
#include <hip/hip_runtime.h>

#define EPS 1e-5f

typedef _Float16 half4_t __attribute__((ext_vector_type(4)));
typedef _Float16 half8_t __attribute__((ext_vector_type(8)));
typedef float floatx4 __attribute__((ext_vector_type(4)));

__device__ __forceinline__ unsigned short f2hb(float f) {
  _Float16 h = (_Float16)f;
  return __builtin_bit_cast(unsigned short, h);
}
__device__ __forceinline__ float hb2f(unsigned short u) {
  return (float)__builtin_bit_cast(_Float16, u);
}
__device__ __forceinline__ unsigned int pack2(float a, float b) {
  return (unsigned int)f2hb(a) | ((unsigned int)f2hb(b) << 16);
}

// ws layout (bytes):
//   qkv_h (fp16 v rows): [512 b][8 g][32 c][64 h]   @ 0         (16,777,216)
//   qkT   (fp16): [512 b][8 g][64 h][32 c]          @ 16777216  (16,777,216)
//   xT    (fp16): [32768 n][256 k]                  @ 33554432  (16,777,216)
//   Wh    (fp16): [512 o][256 k]                    @ 50331648  (262,144)
//   relTq (fp16): [128 t][16 c]                     @ 50593792  (4096)
//   relTk (fp16): [128 t][16 c]                     @ 50597888  (4096)
//   relV  (fp16): [32 c][128 t]                     @ 50601984  (8192)
//   bnsF  (f32) : [8 g][4]                          @ 50610176  (128)
//   bnoSc (f32) : [512]                             @ 50610304  (2048)
//   bnoSh (f32) : [512]                             @ 50612352  (2048)
#define WS_QKT 16777216
#define WS_XT 33554432
#define WS_WH 50331648
#define WS_RELTQ 50593792
#define WS_RELTK 50597888
#define WS_RELV 50601984
#define WS_BNSF 50610176
#define WS_BNOSC 50610304
#define WS_BNOSH 50612352

// ---------------------------------------------------------------------------
// Kernel 0: prep.  blocks 0..2047: transpose-convert x -> xT fp16 (64x64
// tiles via LDS, both sides coalesced). blocks 2048..2055: W -> Wh fp16.
// block 2056: rel tables + folded BN coeffs.
// ---------------------------------------------------------------------------
__global__ __launch_bounds__(256) void k_prep(const float* __restrict__ x,
                                              const float* __restrict__ W,
                                              const float* __restrict__ rel,
                                              const float* __restrict__ bns,
                                              const float* __restrict__ bno,
                                              char* __restrict__ ws) {
  const int bid = blockIdx.x, tid = threadIdx.x;
  if (bid < 2048) {
    __shared__ unsigned short Lt[64 * 72];  // [nloc][kloc], stride 72 (144B rows)
    const int k0 = (bid >> 9) * 64;
    const int n0 = (bid & 511) * 64;
    {
      const int kloc = tid >> 2, c0 = (tid & 3) * 16;
#pragma unroll
      for (int u = 0; u < 4; ++u) {
        const float4 v =
            *reinterpret_cast<const float4*>(&x[(size_t)(k0 + kloc) * 32768 + n0 + c0 + u * 4]);
        Lt[(c0 + u * 4 + 0) * 72 + kloc] = f2hb(v.x);
        Lt[(c0 + u * 4 + 1) * 72 + kloc] = f2hb(v.y);
        Lt[(c0 + u * 4 + 2) * 72 + kloc] = f2hb(v.z);
        Lt[(c0 + u * 4 + 3) * 72 + kloc] = f2hb(v.w);
      }
    }
    __syncthreads();
    {
      unsigned short* xT = (unsigned short*)(ws + WS_XT);
      const int nloc = tid >> 2, kc = (tid & 3) * 16;
      const uint4 a = *reinterpret_cast<const uint4*>(&Lt[nloc * 72 + kc]);
      const uint4 b = *reinterpret_cast<const uint4*>(&Lt[nloc * 72 + kc + 8]);
      uint4* dst = reinterpret_cast<uint4*>(
          &((unsigned short*)(ws + WS_XT))[(size_t)(n0 + nloc) * 256 + k0 + kc]);
      (void)xT;
      dst[0] = a;
      dst[1] = b;
    }
  } else if (bid < 2056) {
    unsigned short* Wh = (unsigned short*)(ws + WS_WH);
    const int base = (bid - 2048) * 16384;
#pragma unroll
    for (int u = 0; u < 16; ++u) {
      const int i = base + u * 1024 + tid * 4;
      const float4 v = *reinterpret_cast<const float4*>(&W[i]);
      uint2 p;
      p.x = pack2(v.x, v.y);
      p.y = pack2(v.z, v.w);
      *reinterpret_cast<uint2*>(&Wh[i]) = p;
    }
  } else {
    unsigned short* relTq = (unsigned short*)(ws + WS_RELTQ);
    unsigned short* relTk = (unsigned short*)(ws + WS_RELTK);
    unsigned short* relV = (unsigned short*)(ws + WS_RELV);
    float* bnsF = (float*)(ws + WS_BNSF);
    float* bnoSc = (float*)(ws + WS_BNOSC);
    float* bnoSh = (float*)(ws + WS_BNOSH);
    for (int idx = tid; idx < 2048; idx += 256) {
      const int t = idx >> 4, c = idx & 15;
      relTq[idx] = (t < 127) ? f2hb(rel[c * 127 + t]) : (unsigned short)0;
      relTk[idx] = (t < 127) ? f2hb(rel[(16 + c) * 127 + t]) : (unsigned short)0;
    }
    for (int idx = tid; idx < 4096; idx += 256) {
      const int c = idx >> 7, t = idx & 127;
      relV[idx] = (t < 127) ? f2hb(rel[(32 + c) * 127 + t]) : (unsigned short)0;
    }
    if (tid < 8) {
      const int g = tid;
      const float scA = bns[g] / sqrtf(bns[72 + g] + EPS);
      const float scB = bns[8 + g] / sqrtf(bns[72 + 8 + g] + EPS);
      const float scC = bns[16 + g] / sqrtf(bns[72 + 16 + g] + EPS);
      const float shv = (bns[24 + g] - bns[48 + g] * scA) +
                        (bns[24 + 8 + g] - bns[48 + 8 + g] * scB) +
                        (bns[24 + 16 + g] - bns[48 + 16 + g] * scC);
      bnsF[g * 4 + 0] = scA;
      bnsF[g * 4 + 1] = scB;
      bnsF[g * 4 + 2] = scC;
      bnsF[g * 4 + 3] = shv;
    }
    for (int idx = tid; idx < 512; idx += 256) {
      const float sc = bno[idx] / sqrtf(bno[1536 + idx] + EPS);
      bnoSc[idx] = sc;
      bnoSh[idx] = bno[512 + idx] - bno[1024 + idx] * sc;
    }
  }
}

// ---------------------------------------------------------------------------
// Kernel 1: qkv = BN(Wh @ xT^T), fp16 MFMA, zero-LDS K-loop.
// Grid 1024: xcd=bid&7, g=(bid>>3)&7, bq=bid>>6; wave wid owns b-slice
// b = (xcd*16+bq)*4+wid, full 64o x 64n tile (acc[4][4], 128 MFMA).
// All fragments are direct 16B global loads (Wh 256KB + per-XCD xT slice
// 2MB, L2-resident). Epilogue: BN; q/k -> LDS transpose -> coalesced qkT;
// v -> qkv_h.
// ---------------------------------------------------------------------------
__global__ __launch_bounds__(256) void k_qkv_gemm(const float* __restrict__ bnq,
                                                  char* __restrict__ ws) {
  const unsigned short* xT = (const unsigned short*)(ws + WS_XT);
  const unsigned short* Wh = (const unsigned short*)(ws + WS_WH);
  unsigned short* qkv_h = (unsigned short*)ws;
  unsigned short* qkT = (unsigned short*)(ws + WS_QKT);
  __shared__ unsigned short Tq[4][32 * 72];  // per-wave q/k transpose buffer

  const int tid = threadIdx.x;
  const int lane = tid & 63;
  const int wid = tid >> 6;
  const int l15 = lane & 15, kg = lane >> 4;
  const int xcd = blockIdx.x & 7;
  const int seq = blockIdx.x >> 3;
  const int g = seq & 7;
  const int bq = seq >> 3;  // 0..15
  const size_t bbase = (size_t)(xcd * 16 + bq) * 4;
  const size_t bb = bbase + wid;
  const int o0 = g * 64;

  floatx4 acc[4][4] = {};
  const unsigned short* aBase = Wh + (size_t)(o0 + l15) * 256 + kg * 8;
  const unsigned short* bBase = xT + (bb * 64 + l15) * 256 + kg * 8;

#pragma unroll
  for (int kk = 0; kk < 8; ++kk) {
    half8_t af[4], bf[4];
#pragma unroll
    for (int fm = 0; fm < 4; ++fm)
      af[fm] = *reinterpret_cast<const half8_t*>(aBase + fm * 4096 + kk * 32);
#pragma unroll
    for (int fn = 0; fn < 4; ++fn)
      bf[fn] = *reinterpret_cast<const half8_t*>(bBase + fn * 4096 + kk * 32);
#pragma unroll
    for (int fm = 0; fm < 4; ++fm)
#pragma unroll
      for (int fn = 0; fn < 4; ++fn)
        acc[fm][fn] = __builtin_amdgcn_mfma_f32_16x16x32_f16(af[fm], bf[fn], acc[fm][fn], 0, 0, 0);
  }

  // ---- epilogue: BN; q/k rows -> Tq[wid]; v rows -> qkv_h ----
#pragma unroll
  for (int fm = 0; fm < 4; ++fm) {
    float sc[4], sh[4];
#pragma unroll
    for (int reg = 0; reg < 4; ++reg) {
      const int o = o0 + fm * 16 + kg * 4 + reg;
      sc[reg] = bnq[o] / sqrtf(bnq[1536 + o] + EPS);
      sh[reg] = bnq[512 + o] - bnq[1024 + o] * sc[reg];
    }
#pragma unroll
    for (int fn = 0; fn < 4; ++fn) {
      const int h = fn * 16 + l15;
#pragma unroll
      for (int reg = 0; reg < 4; ++reg) {
        const int row = fm * 16 + kg * 4 + reg;  // o % 64
        const float val = fmaf(acc[fm][fn][reg], sc[reg], sh[reg]);
        if (fm < 2) {
          Tq[wid][row * 72 + h] = f2hb(val);  // q/k rows 0..31
        } else {
          qkv_h[((bb * 8 + g) * 32 + (row - 32)) * 64 + h] = f2hb(val);
        }
      }
    }
  }
  __syncthreads();
  // cooperative coalesced qkT stores, one tile per iteration
#pragma unroll
  for (int t4 = 0; t4 < 4; ++t4) {
    const size_t btile = bbase + t4;
    const int h = tid >> 2, c0 = (tid & 3) * 8;
    unsigned short tmp[8];
#pragma unroll
    for (int e = 0; e < 8; ++e) tmp[e] = Tq[t4][(c0 + e) * 72 + h];
    uint4 wv;
    wv.x = (unsigned int)tmp[0] | ((unsigned int)tmp[1] << 16);
    wv.y = (unsigned int)tmp[2] | ((unsigned int)tmp[3] << 16);
    wv.z = (unsigned int)tmp[4] | ((unsigned int)tmp[5] << 16);
    wv.w = (unsigned int)tmp[6] | ((unsigned int)tmp[7] << 16);
    *reinterpret_cast<uint4*>(&qkT[((btile * 8 + g) * 64 + h) * 32 + c0]) = wv;
  }
}

// ---------------------------------------------------------------------------
// Kernel 2: per (b,g) attention, fp16 MFMA, in-register softmax. (r9 structure)
// ---------------------------------------------------------------------------
#define QKS 36   // qkL row stride (halves)
#define M1S 132  // M1/M2 row stride (halves)
#define PBS 72   // Pb / Vb row stride (halves)
#define PPS 136  // Pp row stride (halves)
#define OTS 67   // out-tile row stride (floats)

__global__ __launch_bounds__(256, 4) void k_attn(const char* __restrict__ ws,
                                                 float* __restrict__ out) {
  const unsigned short* qkv_h = (const unsigned short*)ws;
  const unsigned short* qkTg = (const unsigned short*)(ws + WS_QKT);
  const unsigned short* relTq = (const unsigned short*)(ws + WS_RELTQ);
  const unsigned short* relTk = (const unsigned short*)(ws + WS_RELTK);
  const unsigned short* relV = (const unsigned short*)(ws + WS_RELV);
  const float* bnsF = (const float*)(ws + WS_BNSF);
  const float* bnoSc = (const float*)(ws + WS_BNOSC);
  const float* bnoSh = (const float*)(ws + WS_BNOSH);

  __shared__ __align__(16) char arena[38400];
  unsigned short* qkL = (unsigned short*)arena;                    // [64][36]  4608  (ph1-2)
  unsigned short* M1 = (unsigned short*)(arena + 4608);            // [64][132] 16896 (ph2-3a)
  unsigned short* M2 = (unsigned short*)(arena + 21504);           // [64][132] 16896
  unsigned short* Pb = (unsigned short*)arena;                     // [64][72]  9216  (ph3b-5)
  unsigned short* Pp = (unsigned short*)(arena + 9216);            // [64][136] 17408
  unsigned short* Vb = (unsigned short*)(arena + 26624);           // [32][72]  4608
  float* Sout = (float*)arena;                                     // [32][67]  8576  (epilogue)

  const int tid = threadIdx.x;
  const int lane = tid & 63;
  const int wid = tid >> 6;
  const int l15 = lane & 15, kg = lane >> 4;
  const int bg = blockIdx.x;
  const int b = bg >> 3, g = bg & 7;

  // ---- phase 1: stage qkT block (64x32 fp16, 4KB) ----
  {
    const uint4 qv =
        *reinterpret_cast<const uint4*>(&qkTg[(size_t)(((b << 3) + g)) * 2048 + tid * 8]);
    const int i = tid >> 2, c0 = (tid & 3) * 8;
    uint2 lo, hi;
    lo.x = qv.x; lo.y = qv.y; hi.x = qv.z; hi.y = qv.w;
    *reinterpret_cast<uint2*>(&qkL[i * QKS + c0]) = lo;
    *reinterpret_cast<uint2*>(&qkL[i * QKS + c0 + 4]) = hi;
  }
  __syncthreads();

  // ---- phase 2: K=16 MFMAs: qk (regs), M1 = q^T rel_q, M2 = k^T rel_k ----
  floatx4 qkreg[4];
  {
    half4_t brq[8], brk[8];
#pragma unroll
    for (int nt = 0; nt < 8; ++nt) {
      brq[nt] = *reinterpret_cast<const half4_t*>(&relTq[(nt * 16 + l15) * 16 + kg * 4]);
      brk[nt] = *reinterpret_cast<const half4_t*>(&relTk[(nt * 16 + l15) * 16 + kg * 4]);
    }
    const half4_t aq = *reinterpret_cast<const half4_t*>(&qkL[(wid * 16 + l15) * QKS + kg * 4]);
    const half4_t ak =
        *reinterpret_cast<const half4_t*>(&qkL[(wid * 16 + l15) * QKS + 16 + kg * 4]);
#pragma unroll
    for (int nt = 0; nt < 4; ++nt) {
      const half4_t bq =
          *reinterpret_cast<const half4_t*>(&qkL[(nt * 16 + l15) * QKS + 16 + kg * 4]);
      const floatx4 z = {};
      qkreg[nt] = __builtin_amdgcn_mfma_f32_16x16x16f16(aq, bq, z, 0, 0, 0);
    }
#pragma unroll
    for (int nt = 0; nt < 8; ++nt) {
      const floatx4 z = {};
      const floatx4 cr = __builtin_amdgcn_mfma_f32_16x16x16f16(aq, brq[nt], z, 0, 0, 0);
#pragma unroll
      for (int r = 0; r < 4; ++r)
        M1[(wid * 16 + kg * 4 + r) * M1S + nt * 16 + l15] = f2hb(cr[r]);
    }
#pragma unroll
    for (int nt = 0; nt < 8; ++nt) {
      const floatx4 z = {};
      const floatx4 cr = __builtin_amdgcn_mfma_f32_16x16x16f16(ak, brk[nt], z, 0, 0, 0);
#pragma unroll
      for (int r = 0; r < 4; ++r)
        M2[(wid * 16 + kg * 4 + r) * M1S + nt * 16 + l15] = f2hb(cr[r]);
    }
  }
  __syncthreads();

  // ---- phase 3a: gather M1/M2, assemble S in registers; prefetch V ----
  const uint4 vld = *reinterpret_cast<const uint4*>(
      &qkv_h[(((size_t)b * 8 + g) * 32 + (tid >> 3)) * 64 + (tid & 7) * 8]);
  float sreg[4][4];
  {
    const float4 bf = *reinterpret_cast<const float4*>(&bnsF[g * 4]);
#pragma unroll
    for (int nt = 0; nt < 4; ++nt) {
      const int j = nt * 16 + l15;
#pragma unroll
      for (int r = 0; r < 4; ++r) {
        const int i = wid * 16 + kg * 4 + r;
        const int d = i - j + 63;  // 0..126
        const float qr = hb2f(M1[i * M1S + d]);
        const float kr = hb2f(M2[j * M1S + 126 - d]);
        sreg[nt][r] = fmaf(bf.x, qkreg[nt][r], fmaf(bf.y, qr, fmaf(bf.z, kr, bf.w)));
      }
    }
  }
  __syncthreads();  // M1/M2 dead; Pb/Pp/Vb overlay live

  // ---- phase 3b: in-register softmax; write Pb, Pp (+zero complement), Vb ----
  float sm[4];
#pragma unroll
  for (int r = 0; r < 4; ++r) {
    float m = fmaxf(fmaxf(sreg[0][r], sreg[1][r]), fmaxf(sreg[2][r], sreg[3][r]));
    m = fmaxf(m, __shfl_xor(m, 1));
    m = fmaxf(m, __shfl_xor(m, 2));
    m = fmaxf(m, __shfl_xor(m, 4));
    m = fmaxf(m, __shfl_xor(m, 8));
    float s = 0.f;
#pragma unroll
    for (int nt = 0; nt < 4; ++nt) {
      sreg[nt][r] = __expf(sreg[nt][r] - m);
      s += sreg[nt][r];
    }
    s += __shfl_xor(s, 1);
    s += __shfl_xor(s, 2);
    s += __shfl_xor(s, 4);
    s += __shfl_xor(s, 8);
    sm[r] = s;
  }
#pragma unroll
  for (int r = 0; r < 4; ++r) {
    const int i = wid * 16 + kg * 4 + r;
#pragma unroll
    for (int nt = 0; nt < 4; ++nt) {
      const int j = nt * 16 + l15;
      const unsigned short pv = f2hb(sreg[nt][r]);
      Pb[i * PBS + j] = pv;
      Pp[i * PPS + i + 63 - j] = pv;
    }
#pragma unroll
    for (int e = 0; e < 4; ++e) {  // zero complement of [i, i+63] in [0,128)
      const int z = l15 * 4 + e;
      const int t = (z < i) ? z : z + 64;
      Pp[i * PPS + t] = 0;
    }
  }
  {
    *reinterpret_cast<uint4*>(&Vb[(tid >> 3) * PBS + (tid & 7) * 8]) = vld;
  }
  __syncthreads();

  // ---- phase 5: sv / sve MFMAs (fp16 K=32) ----
  floatx4 sva[2] = {}, svea[2] = {};
#pragma unroll
  for (int kk = 0; kk < 2; ++kk) {
    const half8_t pa =
        *reinterpret_cast<const half8_t*>(&Pb[(wid * 16 + l15) * PBS + kk * 32 + kg * 8]);
#pragma unroll
    for (int nt = 0; nt < 2; ++nt) {
      const half8_t vb =
          *reinterpret_cast<const half8_t*>(&Vb[(nt * 16 + l15) * PBS + kk * 32 + kg * 8]);
      sva[nt] = __builtin_amdgcn_mfma_f32_16x16x32_f16(pa, vb, sva[nt], 0, 0, 0);
    }
  }
#pragma unroll
  for (int kk = 0; kk < 4; ++kk) {
    const half8_t pp =
        *reinterpret_cast<const half8_t*>(&Pp[(wid * 16 + l15) * PPS + kk * 32 + kg * 8]);
#pragma unroll
    for (int nt = 0; nt < 2; ++nt) {
      const half8_t rb =
          *reinterpret_cast<const half8_t*>(&relV[(nt * 16 + l15) * 128 + kk * 32 + kg * 8]);
      svea[nt] = __builtin_amdgcn_mfma_f32_16x16x32_f16(pp, rb, svea[nt], 0, 0, 0);
    }
  }
  __syncthreads();  // all Pb/Pp/Vb reads done; Sout overlays

  // ---- epilogue: BN (precomputed coeffs) + out-tile + coalesced store ----
#pragma unroll
  for (int nt = 0; nt < 2; ++nt) {
    const int c = nt * 16 + l15;
    const int ch = ((g << 5) + c) * 2;
    const float2 scv = *reinterpret_cast<const float2*>(&bnoSc[ch]);
    const float2 shv = *reinterpret_cast<const float2*>(&bnoSh[ch]);
#pragma unroll
    for (int r = 0; r < 4; ++r) {
      const int i = wid * 16 + kg * 4 + r;
      const float inv = 1.0f / sm[r];
      Sout[c * OTS + i] =
          fmaf(scv.x, sva[nt][r] * inv, shv.x) + fmaf(scv.y, svea[nt][r] * inv, shv.y);
    }
  }
  __syncthreads();
  {
    const size_t outbase = (size_t)b * 64;
#pragma unroll
    for (int r = 0; r < 8; ++r) {
      const int idx = tid + r * 256;
      const int cc = idx >> 6, ii = idx & 63;
      out[(size_t)((g << 5) + cc) * 32768 + outbase + ii] = Sout[cc * OTS + ii];
    }
  }
}

extern "C" void kernel_launch(void* const* d_in, const int* in_sizes, int n_in,
                              void* d_out, int out_size, void* d_ws, size_t ws_size,
                              hipStream_t stream) {
  const float* x = (const float*)d_in[0];         // (1,256,16,32,64)
  const float* qkv_w = (const float*)d_in[1];     // (512,256)
  const float* relative = (const float*)d_in[2];  // (64,127)
  const float* bn_qkv = (const float*)d_in[3];    // (4,512)
  const float* bn_sim = (const float*)d_in[4];    // (4,24)
  const float* bn_out = (const float*)d_in[5];    // (4,512)
  float* out = (float*)d_out;                     // (256, 512, 64) as [op][b][h]
  char* ws = (char*)d_ws;

  k_prep<<<2057, 256, 0, stream>>>(x, qkv_w, relative, bn_sim, bn_out, ws);
  k_qkv_gemm<<<1024, 256, 0, stream>>>(bn_qkv, ws);
  k_attn<<<4096, 256, 0, stream>>>(ws, out);
}

// Round 14
// 93.895 us; speedup vs baseline: 1.0650x; 1.0650x over previous
//
#include <hip/hip_runtime.h>

#define EPS 1e-5f

typedef _Float16 half4_t __attribute__((ext_vector_type(4)));
typedef _Float16 half8_t __attribute__((ext_vector_type(8)));
typedef float floatx4 __attribute__((ext_vector_type(4)));

__device__ __forceinline__ unsigned short f2hb(float f) {
  _Float16 h = (_Float16)f;
  return __builtin_bit_cast(unsigned short, h);
}
__device__ __forceinline__ float hb2f(unsigned short u) {
  return (float)__builtin_bit_cast(_Float16, u);
}
__device__ __forceinline__ unsigned int pack2(float a, float b) {
  return (unsigned int)f2hb(a) | ((unsigned int)f2hb(b) << 16);
}

// ws layout (bytes):
//   qkv_h (fp16 v rows): [512 b][8 g][32 c][64 h]   @ 0         (16,777,216)
//   qkT   (fp16): [512 b][8 g][64 h][32 c]          @ 16777216  (16,777,216)
//   Wh    (fp16): [512 o][256 k]                    @ 33554432  (262,144)
//   relTq (fp16): [128 t][16 c]                     @ 33816576  (4096)
//   relTk (fp16): [128 t][16 c]                     @ 33820672  (4096)
//   relV  (fp16): [32 c][128 t]                     @ 33824768  (8192)
//   bnsF  (f32) : [8 g][4]                          @ 33832960  (128)
//   bnoSc (f32) : [512]                             @ 33833088  (2048)
//   bnoSh (f32) : [512]                             @ 33835136  (2048)
#define WS_QKT 16777216
#define WS_WH 33554432
#define WS_RELTQ 33816576
#define WS_RELTK 33820672
#define WS_RELV 33824768
#define WS_BNSF 33832960
#define WS_BNOSC 33833088
#define WS_BNOSH 33835136

// ---------------------------------------------------------------------------
// Kernel 0: tiny prep. blocks 0..7: W -> Wh fp16. block 8: rel tables + BN.
// ---------------------------------------------------------------------------
__global__ __launch_bounds__(256) void k_prep(const float* __restrict__ W,
                                              const float* __restrict__ rel,
                                              const float* __restrict__ bns,
                                              const float* __restrict__ bno,
                                              char* __restrict__ ws) {
  const int bid = blockIdx.x, tid = threadIdx.x;
  if (bid < 8) {
    unsigned short* Wh = (unsigned short*)(ws + WS_WH);
    const int base = bid * 16384;
#pragma unroll
    for (int u = 0; u < 16; ++u) {
      const int i = base + u * 1024 + tid * 4;
      const float4 v = *reinterpret_cast<const float4*>(&W[i]);
      uint2 p;
      p.x = pack2(v.x, v.y);
      p.y = pack2(v.z, v.w);
      *reinterpret_cast<uint2*>(&Wh[i]) = p;
    }
  } else {
    unsigned short* relTq = (unsigned short*)(ws + WS_RELTQ);
    unsigned short* relTk = (unsigned short*)(ws + WS_RELTK);
    unsigned short* relV = (unsigned short*)(ws + WS_RELV);
    float* bnsF = (float*)(ws + WS_BNSF);
    float* bnoSc = (float*)(ws + WS_BNOSC);
    float* bnoSh = (float*)(ws + WS_BNOSH);
    for (int idx = tid; idx < 2048; idx += 256) {
      const int t = idx >> 4, c = idx & 15;
      relTq[idx] = (t < 127) ? f2hb(rel[c * 127 + t]) : (unsigned short)0;
      relTk[idx] = (t < 127) ? f2hb(rel[(16 + c) * 127 + t]) : (unsigned short)0;
    }
    for (int idx = tid; idx < 4096; idx += 256) {
      const int c = idx >> 7, t = idx & 127;
      relV[idx] = (t < 127) ? f2hb(rel[(32 + c) * 127 + t]) : (unsigned short)0;
    }
    if (tid < 8) {
      const int g = tid;
      const float scA = bns[g] / sqrtf(bns[72 + g] + EPS);
      const float scB = bns[8 + g] / sqrtf(bns[72 + 8 + g] + EPS);
      const float scC = bns[16 + g] / sqrtf(bns[72 + 16 + g] + EPS);
      const float shv = (bns[24 + g] - bns[48 + g] * scA) +
                        (bns[24 + 8 + g] - bns[48 + 8 + g] * scB) +
                        (bns[24 + 16 + g] - bns[48 + 16 + g] * scC);
      bnsF[g * 4 + 0] = scA;
      bnsF[g * 4 + 1] = scB;
      bnsF[g * 4 + 2] = scC;
      bnsF[g * 4 + 3] = shv;
    }
    for (int idx = tid; idx < 512; idx += 256) {
      const float sc = bno[idx] / sqrtf(bno[1536 + idx] + EPS);
      bnoSc[idx] = sc;
      bnoSh[idx] = bno[512 + idx] - bno[1024 + idx] * sc;
    }
  }
}

// ---------------------------------------------------------------------------
// Kernel 1: fused qkv = BN(Wh @ x-slice). One block per b (512 blocks, 8
// waves). Phase A: x slice -> xT_lds fp16 (read x once, no HBM round-trip).
// Phase B: wave w (= group g) computes 64o x 64n tile; A-frags from L2-hot
// Wh, B-frags from LDS. Phase C: BN -> LDS relayout -> coalesced uint4
// stores of qkT ([h][c]) and qkv_h ([c][h]).
// ---------------------------------------------------------------------------
__global__ __launch_bounds__(512, 4) void k_qkv(const float* __restrict__ x,
                                                const float* __restrict__ bnq,
                                                char* __restrict__ ws) {
  const unsigned short* Wh = (const unsigned short*)(ws + WS_WH);
  unsigned short* qkv_h = (unsigned short*)ws;
  unsigned short* qkT = (unsigned short*)(ws + WS_QKT);
  __shared__ __align__(16) char arena[67584];
  unsigned short* xT = (unsigned short*)arena;            // [64 n][280] 35840B (ph A-B)
  unsigned short* qk_t = (unsigned short*)arena;          // [8 g][64 h][33] 33792B (ph C)
  unsigned short* v_t = (unsigned short*)(arena + 33792); // [8 g][32 c][66] 33792B (ph C)

  const int tid = threadIdx.x;
  const int lane = tid & 63;
  const int w = tid >> 6;  // wave index == group g
  const int l15 = lane & 15, kg = lane >> 4;
  const size_t b = blockIdx.x;
  const int n0g = (int)b * 64;

  // ---- phase A: stage x slice -> xT fp16 [n][k], stride 280 ----
  {
    const int k = tid >> 1;          // 0..255
    const int nb = (tid & 1) * 32;   // 0 / 32
    const float* src = x + (size_t)k * 32768 + n0g + nb;
    unsigned short hv[32];
#pragma unroll
    for (int u = 0; u < 8; ++u) {
      const float4 v4 = *reinterpret_cast<const float4*>(src + u * 4);
      hv[u * 4 + 0] = f2hb(v4.x);
      hv[u * 4 + 1] = f2hb(v4.y);
      hv[u * 4 + 2] = f2hb(v4.z);
      hv[u * 4 + 3] = f2hb(v4.w);
    }
#pragma unroll
    for (int e = 0; e < 32; ++e) xT[(nb + e) * 280 + k] = hv[e];
  }
  __syncthreads();

  // ---- phase B: GEMM. wave w: o rows [w*64, w*64+64) x 64 n ----
  floatx4 acc[4][4] = {};
#pragma unroll
  for (int kk = 0; kk < 8; ++kk) {
    half8_t af[4], bf[4];
#pragma unroll
    for (int fm = 0; fm < 4; ++fm)
      af[fm] = *reinterpret_cast<const half8_t*>(Wh + (size_t)(w * 64 + fm * 16 + l15) * 256 +
                                                 kk * 32 + kg * 8);
#pragma unroll
    for (int fn = 0; fn < 4; ++fn)
      bf[fn] =
          *reinterpret_cast<const half8_t*>(xT + (fn * 16 + l15) * 280 + kk * 32 + kg * 8);
#pragma unroll
    for (int fm = 0; fm < 4; ++fm)
#pragma unroll
      for (int fn = 0; fn < 4; ++fn)
        acc[fm][fn] = __builtin_amdgcn_mfma_f32_16x16x32_f16(af[fm], bf[fn], acc[fm][fn], 0, 0, 0);
  }
  __syncthreads();  // xT dead; qk_t / v_t overlay live

  // ---- phase C: BN epilogue -> LDS relayout ----
  const int o0 = w * 64;
#pragma unroll
  for (int fm = 0; fm < 4; ++fm) {
    float sc[4], sh[4];
#pragma unroll
    for (int reg = 0; reg < 4; ++reg) {
      const int o = o0 + fm * 16 + kg * 4 + reg;
      sc[reg] = bnq[o] / sqrtf(bnq[1536 + o] + EPS);
      sh[reg] = bnq[512 + o] - bnq[1024 + o] * sc[reg];
    }
#pragma unroll
    for (int fn = 0; fn < 4; ++fn) {
      const int h = fn * 16 + l15;
#pragma unroll
      for (int reg = 0; reg < 4; ++reg) {
        const int row = fm * 16 + kg * 4 + reg;  // o % 64
        const float val = fmaf(acc[fm][fn][reg], sc[reg], sh[reg]);
        if (fm < 2) {
          qk_t[w * 2112 + h * 33 + row] = f2hb(val);  // q/k: [h][c]
        } else {
          v_t[w * 2112 + (row - 32) * 66 + h] = f2hb(val);  // v: [c][h]
        }
      }
    }
  }
  __syncthreads();

  // ---- cooperative coalesced stores: 8 qkT tiles + 8 v tiles ----
  {
    const int half = tid >> 8;  // 0/1: two tiles per iteration
    const int tt = tid & 255;
#pragma unroll
    for (int it = 0; it < 4; ++it) {
      const int g = it * 2 + half;
      {  // qkT tile: [64 h][32 c] contiguous 4KB
        const int h = tt >> 2, c0 = (tt & 3) * 8;
        unsigned short tmp[8];
#pragma unroll
        for (int e = 0; e < 8; ++e) tmp[e] = qk_t[g * 2112 + h * 33 + c0 + e];
        uint4 wv;
        wv.x = (unsigned int)tmp[0] | ((unsigned int)tmp[1] << 16);
        wv.y = (unsigned int)tmp[2] | ((unsigned int)tmp[3] << 16);
        wv.z = (unsigned int)tmp[4] | ((unsigned int)tmp[5] << 16);
        wv.w = (unsigned int)tmp[6] | ((unsigned int)tmp[7] << 16);
        *reinterpret_cast<uint4*>(&qkT[((b * 8 + g) * 64 + h) * 32 + c0]) = wv;
      }
      {  // v tile: [32 c][64 h] contiguous 4KB
        const int c = tt >> 3, h0 = (tt & 7) * 8;
        unsigned short tmp[8];
#pragma unroll
        for (int e = 0; e < 8; ++e) tmp[e] = v_t[g * 2112 + c * 66 + h0 + e];
        uint4 wv;
        wv.x = (unsigned int)tmp[0] | ((unsigned int)tmp[1] << 16);
        wv.y = (unsigned int)tmp[2] | ((unsigned int)tmp[3] << 16);
        wv.z = (unsigned int)tmp[4] | ((unsigned int)tmp[5] << 16);
        wv.w = (unsigned int)tmp[6] | ((unsigned int)tmp[7] << 16);
        *reinterpret_cast<uint4*>(&qkv_h[((b * 8 + g) * 32 + c) * 64 + h0]) = wv;
      }
    }
  }
}

// ---------------------------------------------------------------------------
// Kernel 2: per (b,g) attention, fp16 MFMA, in-register softmax. (unchanged)
// ---------------------------------------------------------------------------
#define QKS 36   // qkL row stride (halves)
#define M1S 132  // M1/M2 row stride (halves)
#define PBS 72   // Pb / Vb row stride (halves)
#define PPS 136  // Pp row stride (halves)
#define OTS 67   // out-tile row stride (floats)

__global__ __launch_bounds__(256, 4) void k_attn(const char* __restrict__ ws,
                                                 float* __restrict__ out) {
  const unsigned short* qkv_h = (const unsigned short*)ws;
  const unsigned short* qkTg = (const unsigned short*)(ws + WS_QKT);
  const unsigned short* relTq = (const unsigned short*)(ws + WS_RELTQ);
  const unsigned short* relTk = (const unsigned short*)(ws + WS_RELTK);
  const unsigned short* relV = (const unsigned short*)(ws + WS_RELV);
  const float* bnsF = (const float*)(ws + WS_BNSF);
  const float* bnoSc = (const float*)(ws + WS_BNOSC);
  const float* bnoSh = (const float*)(ws + WS_BNOSH);

  __shared__ __align__(16) char arena[38400];
  unsigned short* qkL = (unsigned short*)arena;                    // [64][36]  4608  (ph1-2)
  unsigned short* M1 = (unsigned short*)(arena + 4608);            // [64][132] 16896 (ph2-3a)
  unsigned short* M2 = (unsigned short*)(arena + 21504);           // [64][132] 16896
  unsigned short* Pb = (unsigned short*)arena;                     // [64][72]  9216  (ph3b-5)
  unsigned short* Pp = (unsigned short*)(arena + 9216);            // [64][136] 17408
  unsigned short* Vb = (unsigned short*)(arena + 26624);           // [32][72]  4608
  float* Sout = (float*)arena;                                     // [32][67]  8576  (epilogue)

  const int tid = threadIdx.x;
  const int lane = tid & 63;
  const int wid = tid >> 6;
  const int l15 = lane & 15, kg = lane >> 4;
  const int bg = blockIdx.x;
  const int b = bg >> 3, g = bg & 7;

  // ---- phase 1: stage qkT block (64x32 fp16, 4KB) ----
  {
    const uint4 qv =
        *reinterpret_cast<const uint4*>(&qkTg[(size_t)(((b << 3) + g)) * 2048 + tid * 8]);
    const int i = tid >> 2, c0 = (tid & 3) * 8;
    uint2 lo, hi;
    lo.x = qv.x; lo.y = qv.y; hi.x = qv.z; hi.y = qv.w;
    *reinterpret_cast<uint2*>(&qkL[i * QKS + c0]) = lo;
    *reinterpret_cast<uint2*>(&qkL[i * QKS + c0 + 4]) = hi;
  }
  __syncthreads();

  // ---- phase 2: K=16 MFMAs: qk (regs), M1 = q^T rel_q, M2 = k^T rel_k ----
  floatx4 qkreg[4];
  {
    half4_t brq[8], brk[8];
#pragma unroll
    for (int nt = 0; nt < 8; ++nt) {
      brq[nt] = *reinterpret_cast<const half4_t*>(&relTq[(nt * 16 + l15) * 16 + kg * 4]);
      brk[nt] = *reinterpret_cast<const half4_t*>(&relTk[(nt * 16 + l15) * 16 + kg * 4]);
    }
    const half4_t aq = *reinterpret_cast<const half4_t*>(&qkL[(wid * 16 + l15) * QKS + kg * 4]);
    const half4_t ak =
        *reinterpret_cast<const half4_t*>(&qkL[(wid * 16 + l15) * QKS + 16 + kg * 4]);
#pragma unroll
    for (int nt = 0; nt < 4; ++nt) {
      const half4_t bq =
          *reinterpret_cast<const half4_t*>(&qkL[(nt * 16 + l15) * QKS + 16 + kg * 4]);
      const floatx4 z = {};
      qkreg[nt] = __builtin_amdgcn_mfma_f32_16x16x16f16(aq, bq, z, 0, 0, 0);
    }
#pragma unroll
    for (int nt = 0; nt < 8; ++nt) {
      const floatx4 z = {};
      const floatx4 cr = __builtin_amdgcn_mfma_f32_16x16x16f16(aq, brq[nt], z, 0, 0, 0);
#pragma unroll
      for (int r = 0; r < 4; ++r)
        M1[(wid * 16 + kg * 4 + r) * M1S + nt * 16 + l15] = f2hb(cr[r]);
    }
#pragma unroll
    for (int nt = 0; nt < 8; ++nt) {
      const floatx4 z = {};
      const floatx4 cr = __builtin_amdgcn_mfma_f32_16x16x16f16(ak, brk[nt], z, 0, 0, 0);
#pragma unroll
      for (int r = 0; r < 4; ++r)
        M2[(wid * 16 + kg * 4 + r) * M1S + nt * 16 + l15] = f2hb(cr[r]);
    }
  }
  __syncthreads();

  // ---- phase 3a: gather M1/M2, assemble S in registers; prefetch V ----
  const uint4 vld = *reinterpret_cast<const uint4*>(
      &qkv_h[(((size_t)b * 8 + g) * 32 + (tid >> 3)) * 64 + (tid & 7) * 8]);
  float sreg[4][4];
  {
    const float4 bf = *reinterpret_cast<const float4*>(&bnsF[g * 4]);
#pragma unroll
    for (int nt = 0; nt < 4; ++nt) {
      const int j = nt * 16 + l15;
#pragma unroll
      for (int r = 0; r < 4; ++r) {
        const int i = wid * 16 + kg * 4 + r;
        const int d = i - j + 63;  // 0..126
        const float qr = hb2f(M1[i * M1S + d]);
        const float kr = hb2f(M2[j * M1S + 126 - d]);
        sreg[nt][r] = fmaf(bf.x, qkreg[nt][r], fmaf(bf.y, qr, fmaf(bf.z, kr, bf.w)));
      }
    }
  }
  __syncthreads();  // M1/M2 dead; Pb/Pp/Vb overlay live

  // ---- phase 3b: in-register softmax; write Pb, Pp (+zero complement), Vb ----
  float sm[4];
#pragma unroll
  for (int r = 0; r < 4; ++r) {
    float m = fmaxf(fmaxf(sreg[0][r], sreg[1][r]), fmaxf(sreg[2][r], sreg[3][r]));
    m = fmaxf(m, __shfl_xor(m, 1));
    m = fmaxf(m, __shfl_xor(m, 2));
    m = fmaxf(m, __shfl_xor(m, 4));
    m = fmaxf(m, __shfl_xor(m, 8));
    float s = 0.f;
#pragma unroll
    for (int nt = 0; nt < 4; ++nt) {
      sreg[nt][r] = __expf(sreg[nt][r] - m);
      s += sreg[nt][r];
    }
    s += __shfl_xor(s, 1);
    s += __shfl_xor(s, 2);
    s += __shfl_xor(s, 4);
    s += __shfl_xor(s, 8);
    sm[r] = s;
  }
#pragma unroll
  for (int r = 0; r < 4; ++r) {
    const int i = wid * 16 + kg * 4 + r;
#pragma unroll
    for (int nt = 0; nt < 4; ++nt) {
      const int j = nt * 16 + l15;
      const unsigned short pv = f2hb(sreg[nt][r]);
      Pb[i * PBS + j] = pv;
      Pp[i * PPS + i + 63 - j] = pv;
    }
#pragma unroll
    for (int e = 0; e < 4; ++e) {  // zero complement of [i, i+63] in [0,128)
      const int z = l15 * 4 + e;
      const int t = (z < i) ? z : z + 64;
      Pp[i * PPS + t] = 0;
    }
  }
  {
    *reinterpret_cast<uint4*>(&Vb[(tid >> 3) * PBS + (tid & 7) * 8]) = vld;
  }
  __syncthreads();

  // ---- phase 5: sv / sve MFMAs (fp16 K=32) ----
  floatx4 sva[2] = {}, svea[2] = {};
#pragma unroll
  for (int kk = 0; kk < 2; ++kk) {
    const half8_t pa =
        *reinterpret_cast<const half8_t*>(&Pb[(wid * 16 + l15) * PBS + kk * 32 + kg * 8]);
#pragma unroll
    for (int nt = 0; nt < 2; ++nt) {
      const half8_t vb =
          *reinterpret_cast<const half8_t*>(&Vb[(nt * 16 + l15) * PBS + kk * 32 + kg * 8]);
      sva[nt] = __builtin_amdgcn_mfma_f32_16x16x32_f16(pa, vb, sva[nt], 0, 0, 0);
    }
  }
#pragma unroll
  for (int kk = 0; kk < 4; ++kk) {
    const half8_t pp =
        *reinterpret_cast<const half8_t*>(&Pp[(wid * 16 + l15) * PPS + kk * 32 + kg * 8]);
#pragma unroll
    for (int nt = 0; nt < 2; ++nt) {
      const half8_t rb =
          *reinterpret_cast<const half8_t*>(&relV[(nt * 16 + l15) * 128 + kk * 32 + kg * 8]);
      svea[nt] = __builtin_amdgcn_mfma_f32_16x16x32_f16(pp, rb, svea[nt], 0, 0, 0);
    }
  }
  __syncthreads();  // all Pb/Pp/Vb reads done; Sout overlays

  // ---- epilogue: BN (precomputed coeffs) + out-tile + coalesced store ----
#pragma unroll
  for (int nt = 0; nt < 2; ++nt) {
    const int c = nt * 16 + l15;
    const int ch = ((g << 5) + c) * 2;
    const float2 scv = *reinterpret_cast<const float2*>(&bnoSc[ch]);
    const float2 shv = *reinterpret_cast<const float2*>(&bnoSh[ch]);
#pragma unroll
    for (int r = 0; r < 4; ++r) {
      const int i = wid * 16 + kg * 4 + r;
      const float inv = 1.0f / sm[r];
      Sout[c * OTS + i] =
          fmaf(scv.x, sva[nt][r] * inv, shv.x) + fmaf(scv.y, svea[nt][r] * inv, shv.y);
    }
  }
  __syncthreads();
  {
    const size_t outbase = (size_t)b * 64;
#pragma unroll
    for (int r = 0; r < 8; ++r) {
      const int idx = tid + r * 256;
      const int cc = idx >> 6, ii = idx & 63;
      out[(size_t)((g << 5) + cc) * 32768 + outbase + ii] = Sout[cc * OTS + ii];
    }
  }
}

extern "C" void kernel_launch(void* const* d_in, const int* in_sizes, int n_in,
                              void* d_out, int out_size, void* d_ws, size_t ws_size,
                              hipStream_t stream) {
  const float* x = (const float*)d_in[0];         // (1,256,16,32,64)
  const float* qkv_w = (const float*)d_in[1];     // (512,256)
  const float* relative = (const float*)d_in[2];  // (64,127)
  const float* bn_qkv = (const float*)d_in[3];    // (4,512)
  const float* bn_sim = (const float*)d_in[4];    // (4,24)
  const float* bn_out = (const float*)d_in[5];    // (4,512)
  float* out = (float*)d_out;                     // (256, 512, 64) as [op][b][h]
  char* ws = (char*)d_ws;

  k_prep<<<9, 256, 0, stream>>>(qkv_w, relative, bn_sim, bn_out, ws);
  k_qkv<<<512, 512, 0, stream>>>(x, bn_qkv, ws);
  k_attn<<<4096, 256, 0, stream>>>(ws, out);
}